// Round 1
// baseline (351.603 us; speedup 1.0000x reference)
//
#include <hip/hip_runtime.h>

#define BLK     256
#define TBATCH  16      // batch rows per block
#define LLEN    50      // act-list length
#define DIM     256     // embedding dim
#define DIM4    64      // DIM / 4 (float4 units)

__device__ __forceinline__ float sigmoidf_(float x) {
    return 1.0f / (1.0f + __expf(-x));
}

__global__ __launch_bounds__(BLK) void slotgate_fused(
    const int* __restrict__ acts_request,   // (B, 50)
    const int* __restrict__ acts_slot,      // (B, 50)
    const int* __restrict__ acts_value,     // (B, 50)
    const int* __restrict__ slot_names,     // (B, 4)
    const float* __restrict__ emb,          // (V, 256)
    const float* __restrict__ w1,           // (256, 256) row-major [i][j]
    const float* __restrict__ w2,           // (256, 256)
    float* __restrict__ out)                // (B, 4, 256)
{
    __shared__ int    lds_iq[TBATCH * LLEN];
    __shared__ int    lds_is[TBATCH * LLEN];
    __shared__ int    lds_iv[TBATCH * LLEN];
    __shared__ float4 lds_tq [TBATCH * DIM4];   // t_q   tile, [bl][j4]
    __shared__ float4 lds_tsv[TBATCH * DIM4];   // t_s+t_v tile

    const int tid  = threadIdx.x;
    const int b0   = blockIdx.x * TBATCH;
    const int wv   = tid >> 6;    // wave id 0..3
    const int lane = tid & 63;

    // ---- stage indices (coalesced) ----
    for (int t = tid; t < TBATCH * LLEN; t += BLK) {
        lds_iq[t] = acts_request[b0 * LLEN + t];
        lds_is[t] = acts_slot   [b0 * LLEN + t];
        lds_iv[t] = acts_value  [b0 * LLEN + t];
    }
    __syncthreads();

    const float4* emb4 = (const float4*)emb;

    // ---- gather phase: wave wv owns batch rows bl = 4*wv .. 4*wv+3 ----
    float4 aq[4], asv[4];
    #pragma unroll
    for (int c = 0; c < 4; c++) {
        aq [c] = make_float4(0.f, 0.f, 0.f, 0.f);
        asv[c] = make_float4(0.f, 0.f, 0.f, 0.f);
    }
    for (int l = 0; l < LLEN; l++) {
        #pragma unroll
        for (int c = 0; c < 4; c++) {
            const int bl = wv * 4 + c;
            const int iq = lds_iq[bl * LLEN + l];
            const int is = lds_is[bl * LLEN + l];
            const int iv = lds_iv[bl * LLEN + l];
            float4 vq = emb4[iq * DIM4 + lane];
            float4 vs = emb4[is * DIM4 + lane];
            float4 vv = emb4[iv * DIM4 + lane];
            aq [c].x += vq.x; aq [c].y += vq.y; aq [c].z += vq.z; aq [c].w += vq.w;
            asv[c].x += vs.x + vv.x;
            asv[c].y += vs.y + vv.y;
            asv[c].z += vs.z + vv.z;
            asv[c].w += vs.w + vv.w;
        }
    }
    #pragma unroll
    for (int c = 0; c < 4; c++) {
        lds_tq [(wv * 4 + c) * DIM4 + lane] = aq [c];
        lds_tsv[(wv * 4 + c) * DIM4 + lane] = asv[c];
    }
    __syncthreads();

    // ---- matmul phase: thread (ti,tb) computes 4 i-rows x 4 batch rows ----
    const int ti  = tid & 63;   // i-group: i = 4*ti .. 4*ti+3
    const int tb  = tid >> 6;   // bl-group: bl = 4*tb .. 4*tb+3 (wave-uniform)
    const int i0  = ti * 4;
    const int bl0 = tb * 4;

    float accq [4][4] = {};  // [r = i-sub][c = bl-sub] : g_q
    float accsv[4][4] = {};  //                          g_sv

    const float4* w1f = (const float4*)w1;
    const float4* w2f = (const float4*)w2;

    for (int j4 = 0; j4 < DIM4; j4++) {
        float4 wa[4], wb[4], tq[4], ts[4];
        #pragma unroll
        for (int r = 0; r < 4; r++) {
            wa[r] = w1f[(i0 + r) * DIM4 + j4];   // per-thread row stream; L1/L2 hit
            wb[r] = w2f[(i0 + r) * DIM4 + j4];
        }
        #pragma unroll
        for (int c = 0; c < 4; c++) {
            tq[c] = lds_tq [(bl0 + c) * DIM4 + j4];   // wave-uniform broadcast b128
            ts[c] = lds_tsv[(bl0 + c) * DIM4 + j4];
        }
        #pragma unroll
        for (int r = 0; r < 4; r++) {
            #pragma unroll
            for (int c = 0; c < 4; c++) {
                accq [r][c] += wa[r].x * tq[c].x + wa[r].y * tq[c].y
                             + wa[r].z * tq[c].z + wa[r].w * tq[c].w;
                accsv[r][c] += wb[r].x * ts[c].x + wb[r].y * ts[c].y
                             + wb[r].z * ts[c].z + wb[r].w * ts[c].w;
            }
        }
    }

    // ---- epilogue: gates = c_s + sig(c_s*g_q) + sig(c_s*g_sv) ----
    float4* out4 = (float4*)out;
    #pragma unroll
    for (int c = 0; c < 4; c++) {
        const int b = b0 + bl0 + c;
        #pragma unroll
        for (int s = 0; s < 4; s++) {
            const int slot = slot_names[b * 4 + s];
            float4 cs = emb4[slot * DIM4 + ti];
            float4 g;
            g.x = cs.x + sigmoidf_(cs.x * accq[0][c]) + sigmoidf_(cs.x * accsv[0][c]);
            g.y = cs.y + sigmoidf_(cs.y * accq[1][c]) + sigmoidf_(cs.y * accsv[1][c]);
            g.z = cs.z + sigmoidf_(cs.z * accq[2][c]) + sigmoidf_(cs.z * accsv[2][c]);
            g.w = cs.w + sigmoidf_(cs.w * accq[3][c]) + sigmoidf_(cs.w * accsv[3][c]);
            out4[(b * 4 + s) * DIM4 + ti] = g;
        }
    }
}

extern "C" void kernel_launch(void* const* d_in, const int* in_sizes, int n_in,
                              void* d_out, int out_size, void* d_ws, size_t ws_size,
                              hipStream_t stream) {
    const int*   acts_request = (const int*)  d_in[0];
    const int*   acts_slot    = (const int*)  d_in[1];
    const int*   acts_value   = (const int*)  d_in[2];
    const int*   slot_names   = (const int*)  d_in[3];
    const float* ontology_emb = (const float*)d_in[4];
    const float* w1           = (const float*)d_in[5];
    const float* w2           = (const float*)d_in[6];
    float*       out          = (float*)      d_out;

    const int bsz  = in_sizes[0] / LLEN;     // 4096
    const int nblk = bsz / TBATCH;           // 256

    slotgate_fused<<<nblk, BLK, 0, stream>>>(
        acts_request, acts_slot, acts_value, slot_names,
        ontology_emb, w1, w2, out);
}